// Round 6
// baseline (432.393 us; speedup 1.0000x reference)
//
#include <hip/hip_runtime.h>
#include <stdint.h>

typedef __attribute__((ext_vector_type(8))) short short8;
typedef __attribute__((ext_vector_type(4))) short short4v;
typedef __attribute__((ext_vector_type(4))) float floatx4;
typedef _Float16 half2v __attribute__((ext_vector_type(2)));

__device__ __forceinline__ float b2f(unsigned short u) {
  union { unsigned int i; float f; } v; v.i = ((unsigned int)u) << 16; return v.f;
}
__device__ __forceinline__ unsigned short f2b(float f) {
  union { float f; unsigned int i; } v; v.f = f;
  unsigned int i = v.i;
  return (unsigned short)((i + 0x7FFFu + ((i >> 16) & 1u)) >> 16);
}
__device__ __forceinline__ short4v pack4(float a, float b, float c, float d) {
  short4v r;
  r[0] = (short)f2b(a); r[1] = (short)f2b(b); r[2] = (short)f2b(c); r[3] = (short)f2b(d);
  return r;
}

// global -> LDS 16B per lane. lds_base wave-uniform; HW adds lane*16B.
__device__ __forceinline__ void stage16(const unsigned short* g, unsigned short* lds_base) {
  __builtin_amdgcn_global_load_lds((__attribute__((address_space(1))) const unsigned int*)g,
                                   (__attribute__((address_space(3))) unsigned int*)lds_base,
                                   16, 0, 0);
}

// ---------------------------------------------------------------------------
// r3-verified 256x256 engine: BK=32, 8 waves, ring-3, 2 phases/tile,
// counted vmcnt(4), setprio, paired-row zero-conflict swizzle.
// SWZ>0: 1-D grid of 8*SWZ*NXT blocks; xcd owns SWZ contiguous y-tiles,
// NXT x-tiles per row of tiles (bijective when grid %8 == 0).
// ---------------------------------------------------------------------------
template<int SWZ, int NXT>
__global__ __launch_bounds__(512, 2) void gemm256(
    const unsigned short* __restrict__ A, const unsigned short* __restrict__ B,
    unsigned short* __restrict__ Cb, float* __restrict__ Cf,
    const float* __restrict__ rowdiv, const float* __restrict__ bias,
    int K, int lda, int ldb, int ldc,
    long long sA, long long sB, long long sC, long long sRD)
{
  const int tid  = threadIdx.x;
  const int lane = tid & 63;
  const int wave = tid >> 6;          // 0..7
  const int wr = wave >> 2;           // 0..1  (row half: 128 rows)
  const int wc = wave & 3;            // 0..3  (col quarter: 64 cols)
  int m0, n0;
  if constexpr (SWZ > 0) {
    const int lin  = blockIdx.x;
    const int xcd  = lin & 7;
    const int rem  = lin >> 3;
    const int yloc = rem / NXT;
    const int x    = rem - yloc * NXT;
    m0 = (xcd * SWZ + yloc) * 256;
    n0 = x * 256;
  } else {
    m0 = blockIdx.y * 256;
    n0 = blockIdx.x * 256;
  }
  const int bz = blockIdx.z;
  A += (long long)bz * sA;
  B += (long long)bz * sB;
  const float* rd = rowdiv ? rowdiv + (long long)bz * sRD : (const float*)0;

  __shared__ __align__(16) unsigned short lds[3 * 16384];

  floatx4 acc[8][4];
#pragma unroll
  for (int i = 0; i < 8; ++i)
#pragma unroll
    for (int j = 0; j < 4; ++j) acc[i][j] = floatx4{0.f, 0.f, 0.f, 0.f};

  const int t    = (lane & 7) ^ (lane >> 3);
  const int srow = 2 * (lane >> 3) + (t >> 2);
  const int scol = (t & 3) * 8;
  const unsigned short* ga0 = A + (long long)(m0 + wave * 32 + srow) * lda + scol;
  const unsigned short* ga1 = ga0 + 16LL * lda;
  const unsigned short* gb0 = B + (long long)(n0 + wave * 32 + srow) * ldb + scol;
  const unsigned short* gb1 = gb0 + 16LL * ldb;

  const int l15  = lane & 15;
  const int q    = lane >> 4;
  const int rofs = (l15 >> 1) * 64 + (((q + 4 * (l15 & 1)) ^ (l15 >> 1)) * 8);

  short8 af[4], bfv[4];

  auto STAGE_A = [&](int kt, int buf) {
    unsigned short* d = lds + buf * 16384 + wave * 1024;
    stage16(ga0 + kt, d);
    stage16(ga1 + kt, d + 512);
  };
  auto STAGE_B = [&](int kt, int buf) {
    unsigned short* d = lds + buf * 16384 + 8192 + wave * 1024;
    stage16(gb0 + kt, d);
    stage16(gb1 + kt, d + 512);
  };
  auto READ_A = [&](int buf, int base) {
    const unsigned short* Ab = lds + buf * 16384;
#pragma unroll
    for (int i = 0; i < 4; ++i)
      af[i] = *(const short8*)&Ab[(wr * 64 + (base + i) * 8) * 64 + rofs];
  };
  auto READ_B = [&](int buf) {
    const unsigned short* Bb = lds + buf * 16384 + 8192;
#pragma unroll
    for (int j = 0; j < 4; ++j)
      bfv[j] = *(const short8*)&Bb[(wc * 32 + j * 8) * 64 + rofs];
  };
  auto MFMA_BLK = [&](int h) {
#pragma unroll
    for (int i = 0; i < 4; ++i)
#pragma unroll
      for (int j = 0; j < 4; ++j)
        acc[h * 4 + i][j] = __builtin_amdgcn_mfma_f32_16x16x32_bf16(bfv[j], af[i], acc[h * 4 + i][j], 0, 0, 0);
  };

  const int nt = K >> 5;
  int cur = 0;

  STAGE_A(0, 0);  STAGE_B(0, 0);
  STAGE_A(32, 1); STAGE_B(32, 1);
  asm volatile("s_waitcnt vmcnt(4)" ::: "memory");
  __builtin_amdgcn_s_barrier();

  for (int tt = 0; tt < nt - 2; ++tt) {
    const int nb  = (cur == 0) ? 2 : cur - 1;
    const int kt2 = (tt + 2) << 5;
    READ_B(cur);
    READ_A(cur, 0);
    STAGE_A(kt2, nb);
    __builtin_amdgcn_s_barrier();
    __builtin_amdgcn_s_setprio(1);
    MFMA_BLK(0);
    __builtin_amdgcn_s_setprio(0);
    __builtin_amdgcn_s_barrier();
    READ_A(cur, 4);
    STAGE_B(kt2, nb);
    __builtin_amdgcn_s_barrier();
    __builtin_amdgcn_s_setprio(1);
    MFMA_BLK(1);
    __builtin_amdgcn_s_setprio(0);
    asm volatile("s_waitcnt vmcnt(4)" ::: "memory");
    __builtin_amdgcn_s_barrier();
    cur = (cur == 2) ? 0 : cur + 1;
  }
  {
    READ_B(cur);
    READ_A(cur, 0);
    __builtin_amdgcn_s_barrier();
    __builtin_amdgcn_s_setprio(1);
    MFMA_BLK(0);
    __builtin_amdgcn_s_setprio(0);
    __builtin_amdgcn_s_barrier();
    READ_A(cur, 4);
    __builtin_amdgcn_s_setprio(1);
    MFMA_BLK(1);
    __builtin_amdgcn_s_setprio(0);
    asm volatile("s_waitcnt vmcnt(0)" ::: "memory");
    __builtin_amdgcn_s_barrier();
    cur = (cur == 2) ? 0 : cur + 1;
  }
  {
    READ_B(cur);
    READ_A(cur, 0);
    __builtin_amdgcn_s_barrier();
    __builtin_amdgcn_s_setprio(1);
    MFMA_BLK(0);
    __builtin_amdgcn_s_setprio(0);
    READ_A(cur, 4);
    __builtin_amdgcn_s_setprio(1);
    MFMA_BLK(1);
    __builtin_amdgcn_s_setprio(0);
  }

#pragma unroll
  for (int i = 0; i < 8; ++i) {
    const int row = m0 + wr * 128 + i * 16 + l15;
    const float rcp = rd ? __builtin_amdgcn_rcpf(rd[row]) : 1.0f;
#pragma unroll
    for (int j = 0; j < 4; ++j) {
      const int colb = n0 + wc * 64 + j * 16 + q * 4;
      floatx4 v = acc[i][j];
      if (rd) { v[0] *= rcp; v[1] *= rcp; v[2] *= rcp; v[3] *= rcp; }
      if (bias) {
        const float4 bi = *(const float4*)&bias[colb];
        v[0] += bi.x; v[1] += bi.y; v[2] += bi.z; v[3] += bi.w;
      }
      if (Cb) *(short4v*)&Cb[(long long)bz * sC + (long long)row * ldc + colb] = pack4(v[0], v[1], v[2], v[3]);
      else    *(floatx4*)&Cf[(long long)bz * sC + (long long)row * ldc + colb] = v;
    }
  }
}

// ---------------------------------------------------------------------------
// Fused scores + group + exp (verified; qk buffer rows now 1536 wide).
// ---------------------------------------------------------------------------
__global__ __launch_bounds__(256) void score_weights(
    const unsigned short* __restrict__ qkv, const unsigned short* __restrict__ gw,
    unsigned short* __restrict__ Wout, float* __restrict__ L,
    const float* __restrict__ alpha)
{
  const int tid  = threadIdx.x;
  const int lane = tid & 63;
  const int wave = tid >> 6;
  const int wr = wave >> 1, wc = wave & 1;
  const int n0 = blockIdx.x * 128;
  const int m0 = blockIdx.y * 128;
  const int b  = blockIdx.z;

  const int l15 = lane & 15;
  const int q   = lane >> 4;
  const int q8  = q * 8;

  const unsigned short* gq = gw + ((long long)(b * 1024 + m0 + wr * 64)) * 64;
  const unsigned short* gk = gw + ((long long)(b * 1024 + n0 + wc * 64)) * 64;
  floatx4 gacc[4][4];
#pragma unroll
  for (int i = 0; i < 4; ++i)
#pragma unroll
    for (int j = 0; j < 4; ++j) gacc[i][j] = floatx4{0.f, 0.f, 0.f, 0.f};
#pragma unroll
  for (int ks = 0; ks < 2; ++ks) {
    short8 af[4], bfv[4];
#pragma unroll
    for (int i = 0; i < 4; ++i) af[i]  = *(const short8*)&gq[(long long)(i * 16 + l15) * 64 + ks * 32 + q8];
#pragma unroll
    for (int j = 0; j < 4; ++j) bfv[j] = *(const short8*)&gk[(long long)(j * 16 + l15) * 64 + ks * 32 + q8];
#pragma unroll
    for (int i = 0; i < 4; ++i)
#pragma unroll
      for (int j = 0; j < 4; ++j)
        gacc[i][j] = __builtin_amdgcn_mfma_f32_16x16x32_bf16(bfv[j], af[i], gacc[i][j], 0, 0, 0);
  }
  const float aa    = 1.0f / (1.0f + __expf(-alpha[0]));
  const float onema = 1.0f - aa;
  half2v gfp[4][4][2];
#pragma unroll
  for (int i = 0; i < 4; ++i)
#pragma unroll
    for (int j = 0; j < 4; ++j) {
      gfp[i][j][0] = half2v{(_Float16)(aa + onema * gacc[i][j][0]),
                            (_Float16)(aa + onema * gacc[i][j][1])};
      gfp[i][j][1] = half2v{(_Float16)(aa + onema * gacc[i][j][2]),
                            (_Float16)(aa + onema * gacc[i][j][3])};
    }

  const unsigned short* Aq = qkv + ((long long)(b * 1024 + m0)) * 1536;        // q cols 0..767
  const unsigned short* Bk = qkv + ((long long)(b * 1024 + n0)) * 1536 + 768;  // k cols 768..1535

  __shared__ unsigned short As[128 * 32];
  __shared__ unsigned short Bs[128 * 32];

  floatx4 sacc[4][4];
#pragma unroll
  for (int i = 0; i < 4; ++i)
#pragma unroll
    for (int j = 0; j < 4; ++j) sacc[i][j] = floatx4{0.f, 0.f, 0.f, 0.f};

  const int t    = (lane & 7) ^ (lane >> 3);
  const int srow = 2 * (lane >> 3) + (t >> 2);
  const int scol = (t & 3) * 8;
  const unsigned short* ga0 = Aq + (long long)(wave * 32 + srow) * 1536 + scol;
  const unsigned short* ga1 = ga0 + 16LL * 1536;
  const unsigned short* gb0 = Bk + (long long)(wave * 32 + srow) * 1536 + scol;
  const unsigned short* gb1 = gb0 + 16LL * 1536;
  unsigned short* lA0 = As + wave * 1024;
  unsigned short* lA1 = lA0 + 512;
  unsigned short* lB0 = Bs + wave * 1024;
  unsigned short* lB1 = lB0 + 512;

  const int rofs = (l15 >> 1) * 64 + (((q + 4 * (l15 & 1)) ^ (l15 >> 1)) * 8);

  for (int kt = 0; kt < 768; kt += 32) {
    __syncthreads();
    stage16(ga0 + kt, lA0);
    stage16(ga1 + kt, lA1);
    stage16(gb0 + kt, lB0);
    stage16(gb1 + kt, lB1);
    __syncthreads();
    short8 af[4], bfv[4];
#pragma unroll
    for (int i = 0; i < 4; ++i) af[i]  = *(const short8*)&As[(wr * 32 + i * 8) * 64 + rofs];
#pragma unroll
    for (int j = 0; j < 4; ++j) bfv[j] = *(const short8*)&Bs[(wc * 32 + j * 8) * 64 + rofs];
#pragma unroll
    for (int i = 0; i < 4; ++i)
#pragma unroll
      for (int j = 0; j < 4; ++j)
        sacc[i][j] = __builtin_amdgcn_mfma_f32_16x16x32_bf16(bfv[j], af[i], sacc[i][j], 0, 0, 0);
  }

  const float scale = 0.03608439182435161f;
  unsigned short* Wb = Wout + ((long long)b << 20);

#pragma unroll
  for (int i = 0; i < 4; ++i) {
    const int row = m0 + wr * 64 + i * 16 + l15;
    float ls = 0.0f;
#pragma unroll
    for (int j = 0; j < 4; ++j) {
      const int colb = n0 + wc * 64 + j * 16 + q * 4;
      float e0 = __expf(sacc[i][j][0] * scale);
      float e1 = __expf(sacc[i][j][1] * scale);
      float e2 = __expf(sacc[i][j][2] * scale);
      float e3 = __expf(sacc[i][j][3] * scale);
      ls += (e0 + e1) + (e2 + e3);
      *(short4v*)&Wb[(long long)row * 1024 + colb] =
        pack4(e0 * (float)gfp[i][j][0][0], e1 * (float)gfp[i][j][0][1],
              e2 * (float)gfp[i][j][1][0], e3 * (float)gfp[i][j][1][1]);
    }
    ls += __shfl_xor(ls, 16, 64);
    ls += __shfl_xor(ls, 32, 64);
    if (lane < 16) atomicAdd(&L[b * 1024 + row], ls);
  }
}

// ---------------------------------------------------------------------------
// MFMA-based gw (verified r5; qk row stride now 1536).
// ---------------------------------------------------------------------------
__global__ __launch_bounds__(256) void gw_mfma(
    const unsigned short* __restrict__ qkv, const unsigned short* __restrict__ Wgp64,
    unsigned short* __restrict__ gw)
{
  const int lane = threadIdx.x & 63;
  const int wave = threadIdx.x >> 6;
  const int l15  = lane & 15;
  const int q    = lane >> 4;
  const int q8   = q * 8;
  const long long row0 = (long long)blockIdx.x * 64 + wave * 16;
  const unsigned short* A = qkv + row0 * 1536;          // q cols 0..767

  floatx4 acc[4];
#pragma unroll
  for (int j = 0; j < 4; ++j) acc[j] = floatx4{0.f, 0.f, 0.f, 0.f};

  for (int kt = 0; kt < 768; kt += 32) {
    short8 af = *(const short8*)&A[(long long)l15 * 1536 + kt + q8];
    short8 bf[4];
#pragma unroll
    for (int j = 0; j < 4; ++j)
      bf[j] = *(const short8*)&Wgp64[(j * 16 + l15) * 768 + kt + q8];
#pragma unroll
    for (int j = 0; j < 4; ++j)
      acc[j] = __builtin_amdgcn_mfma_f32_16x16x32_bf16(bf[j], af, acc[j], 0, 0, 0);
  }

  float mx = -1e30f;
#pragma unroll
  for (int j = 0; j < 4; ++j)
#pragma unroll
    for (int e = 0; e < 4; ++e) {
      const int col = j * 16 + q * 4 + e;
      if (col < 49) mx = fmaxf(mx, acc[j][e]);
    }
  mx = fmaxf(mx, __shfl_xor(mx, 16, 64));
  mx = fmaxf(mx, __shfl_xor(mx, 32, 64));

  float ev[4][4];
  float s = 0.0f;
#pragma unroll
  for (int j = 0; j < 4; ++j)
#pragma unroll
    for (int e = 0; e < 4; ++e) {
      const int col = j * 16 + q * 4 + e;
      const float x = (col < 49) ? __expf(acc[j][e] - mx) : 0.0f;
      ev[j][e] = x;
      s += x;
    }
  s += __shfl_xor(s, 16, 64);
  s += __shfl_xor(s, 32, 64);
  const float inv = 1.0f / s;

  unsigned short* out = gw + (row0 + l15) * 64;
#pragma unroll
  for (int j = 0; j < 4; ++j)
    *(short4v*)&out[j * 16 + q * 4] =
      pack4(ev[j][0] * inv, ev[j][1] * inv, ev[j][2] * inv, ev[j][3] * inv);
}

__global__ void convert_f2b(const float* __restrict__ in, unsigned short* __restrict__ out, long long n)
{
  long long i = ((long long)blockIdx.x * 256 + threadIdx.x) * 4;
  if (i + 3 >= n) {
    for (long long k = i; k < n; ++k) out[k] = f2b(in[k]);
    return;
  }
  float4 v = *(const float4*)(in + i);
  out[i + 0] = f2b(v.x);
  out[i + 1] = f2b(v.y);
  out[i + 2] = f2b(v.z);
  out[i + 3] = f2b(v.w);
}

__global__ void transpose_f2b(const float* __restrict__ in, unsigned short* __restrict__ out,
                              int R, int C, int ldin, int ldout)
{
  __shared__ unsigned short t[32][33];
  const int c0 = blockIdx.x * 32, r0 = blockIdx.y * 32;
  for (int i = threadIdx.y; i < 32; i += 8) {
    const int r = r0 + i, c = c0 + threadIdx.x;
    if (r < R && c < C) t[i][threadIdx.x] = f2b(in[(long long)r * ldin + c]);
  }
  __syncthreads();
  for (int i = threadIdx.y; i < 32; i += 8) {
    const int r = c0 + i, c = r0 + threadIdx.x;
    if (r < C && c < R) out[(long long)r * ldout + c] = t[threadIdx.x][i];
  }
}

// WvB[768][768] bf16 = W_qkv[:, 1536:2304] (row-major slice convert)
__global__ void slice_f2b(const float* __restrict__ in, unsigned short* __restrict__ out)
{
  const long long idx = (long long)blockIdx.x * 256 + threadIdx.x;  // < 589824
  const int r = (int)(idx / 768), c = (int)(idx - (long long)r * 768);
  out[idx] = f2b(in[(long long)r * 2304 + 1536 + c]);
}

// bias2[j] = b_proj[j] + sum_d W_proj[d][j] * b_qkv[1536+d]
__global__ __launch_bounds__(256) void bias2_kernel(
    const float* __restrict__ W_proj, const float* __restrict__ b_qkv,
    const float* __restrict__ b_proj, float* __restrict__ bias2)
{
  const int j = blockIdx.x * 256 + threadIdx.x;
  if (j >= 768) return;
  float s = b_proj[j];
#pragma unroll 4
  for (int d = 0; d < 768; ++d) s += W_proj[d * 768 + j] * b_qkv[1536 + d];
  bias2[j] = s;
}

extern "C" void kernel_launch(void* const* d_in, const int* in_sizes, int n_in,
                              void* d_out, int out_size, void* d_ws, size_t ws_size,
                              hipStream_t stream)
{
  const float* x      = (const float*)d_in[0];
  const float* W_qkv  = (const float*)d_in[1];
  const float* b_qkv  = (const float*)d_in[2];
  const float* W_proj = (const float*)d_in[3];
  const float* b_proj = (const float*)d_in[4];
  const float* W_gp   = (const float*)d_in[5];
  const float* alpha  = (const float*)d_in[6];

  char* p = (char*)d_ws;
  auto alloc = [&](size_t bytes) { char* r = p; p += (bytes + 255) & ~255ULL; return r; };
  unsigned short* qk     = (unsigned short*)alloc(16384ULL * 1536 * 2);   // q|k rows
  unsigned short* xb     = (unsigned short*)alloc(16384ULL * 768 * 2);
  unsigned short* WqkvT  = (unsigned short*)alloc(1536ULL * 768 * 2);     // q,k cols only
  unsigned short* WprojT = (unsigned short*)alloc(768ULL * 768 * 2);
  unsigned short* WvB    = (unsigned short*)alloc(768ULL * 768 * 2);      // Wv row-major bf16
  unsigned short* Wcomb  = (unsigned short*)alloc(768ULL * 768 * 2);      // (Wv @ W_proj) row: n, col: k
  unsigned short* Wgp64  = (unsigned short*)alloc(64ULL * 768 * 2);       // zero-padded rows 49..63
  unsigned short* gwbuf  = (unsigned short*)alloc(16384ULL * 64 * 2);
  float*          Lbuf   = (float*)alloc(16384ULL * 4);
  float*          bias2  = (float*)alloc(768ULL * 4);
  unsigned short* wmat   = (unsigned short*)alloc(16ULL * 1024 * 1024 * 2);
  unsigned short* vpT    = (unsigned short*)alloc(16ULL * 768 * 1024 * 2);

  const dim3 blk256(256);
  const dim3 blk512(512);
  const dim3 tb(32, 8);

  // input conversions / transposes (fp32 -> bf16)
  convert_f2b<<<dim3(12288), blk256, 0, stream>>>(x, xb, 16384LL * 768);
  transpose_f2b<<<dim3(48, 24), tb, 0, stream>>>(W_qkv, WqkvT, 768, 1536, 2304, 768);
  transpose_f2b<<<dim3(24, 24), tb, 0, stream>>>(W_proj, WprojT, 768, 768, 768, 768);
  hipMemsetAsync(Wgp64, 0, 64ULL * 768 * 2, stream);
  transpose_f2b<<<dim3(2, 24), tb, 0, stream>>>(W_gp, Wgp64, 768, 49, 49, 768);
  slice_f2b<<<dim3(2304), blk256, 0, stream>>>(W_qkv, WvB);

  // Wcomb[n][k] = sum_d W_projT[n][d] * WvB[k][d]  (= (Wv @ W_proj)^T entry)
  gemm256<0, 1><<<dim3(3, 3, 1), blk512, 0, stream>>>(WprojT, WvB, Wcomb, (float*)0,
                                                      (const float*)0, (const float*)0,
                                                      768, 768, 768, 768, 0, 0, 0, 0);
  // bias2 = b_proj + W_proj^T @ b_qkv[1536:2304]
  bias2_kernel<<<dim3(3), blk256, 0, stream>>>(W_proj, b_qkv, b_proj, bias2);

  // qk = x @ W_qkv[:, :1536] + b_qkv[:1536]   (384 = 8 xcd * 8 ytiles * 6 xtiles)
  gemm256<8, 6><<<dim3(384, 1, 1), blk512, 0, stream>>>(xb, WqkvT, qk, (float*)0,
                                                        (const float*)0, b_qkv,
                                                        768, 768, 768, 1536, 0, 0, 0, 0);

  // gw = softmax(q @ W_gp), padded to 64
  gw_mfma<<<dim3(256), blk256, 0, stream>>>(qk, Wgp64, gwbuf);

  hipMemsetAsync(Lbuf, 0, 16384 * 4, stream);

  // weights (unnormalized) + L
  score_weights<<<dim3(8, 8, 16), blk256, 0, stream>>>(qk, gwbuf, wmat, Lbuf, alpha);

  // vpT[b][n][m] = sum_k Wcomb[n][k] * x[b][m][k]   (v never materialized)
  gemm256<0, 1><<<dim3(4, 3, 16), blk512, 0, stream>>>(Wcomb, xb, vpT, (float*)0,
                                                       (const float*)0, (const float*)0,
                                                       768, 768, 768, 1024,
                                                       0, 1024LL * 768, 768LL * 1024, 0);

  // out[m][j] = (1/L[m]) * sum_n wmat[m][n] * vpT[j][n] + bias2[j]   (fp32 out)
  gemm256<0, 1><<<dim3(3, 4, 16), blk512, 0, stream>>>(wmat, vpT, (unsigned short*)0, (float*)d_out,
                                                       Lbuf, bias2,
                                                       1024, 1024, 1024, 768,
                                                       1024LL * 1024, 768LL * 1024, 1024LL * 768, 1024);
}

// Round 7
// 366.822 us; speedup vs baseline: 1.1788x; 1.1788x over previous
//
#include <hip/hip_runtime.h>
#include <stdint.h>

typedef __attribute__((ext_vector_type(8))) short short8;
typedef __attribute__((ext_vector_type(4))) short short4v;
typedef __attribute__((ext_vector_type(4))) float floatx4;
typedef _Float16 half2v __attribute__((ext_vector_type(2)));

__device__ __forceinline__ float b2f(unsigned short u) {
  union { unsigned int i; float f; } v; v.i = ((unsigned int)u) << 16; return v.f;
}
__device__ __forceinline__ unsigned short f2b(float f) {
  union { float f; unsigned int i; } v; v.f = f;
  unsigned int i = v.i;
  return (unsigned short)((i + 0x7FFFu + ((i >> 16) & 1u)) >> 16);
}
__device__ __forceinline__ short4v pack4(float a, float b, float c, float d) {
  short4v r;
  r[0] = (short)f2b(a); r[1] = (short)f2b(b); r[2] = (short)f2b(c); r[3] = (short)f2b(d);
  return r;
}

// global -> LDS 16B per lane. lds_base wave-uniform; HW adds lane*16B.
__device__ __forceinline__ void stage16(const unsigned short* g, unsigned short* lds_base) {
  __builtin_amdgcn_global_load_lds((__attribute__((address_space(1))) const unsigned int*)g,
                                   (__attribute__((address_space(3))) unsigned int*)lds_base,
                                   16, 0, 0);
}

// ---------------------------------------------------------------------------
// r0-verified 128x128 BK=32 engine: paired-row LDS swizzle (0 conflicts),
// swapped-operand MFMA, 56 VGPR -> ~3 blocks/CU. Best engine at every grid
// in this problem (occupancy beats ILP; r0 vs r5 parity at 768 blocks,
// 128² wins below).  SYT>0: 1-D grid 8*SYT*SXT, xcd owns SYT contiguous
// y-tiles (bijective since grid%8==0).
// ---------------------------------------------------------------------------
template<int SYT, int SXT>
__global__ __launch_bounds__(256, 4) void gemm_bt(
    const unsigned short* __restrict__ A, const unsigned short* __restrict__ B,
    unsigned short* __restrict__ Cb, float* __restrict__ Cf,
    const float* __restrict__ rowdiv, const float* __restrict__ bias,
    int K, int lda, int ldb, int ldc,
    long long sA, long long sB, long long sC, long long sRD)
{
  const int tid  = threadIdx.x;
  const int lane = tid & 63;
  const int wave = tid >> 6;
  const int wr = wave >> 1, wc = wave & 1;
  int m0, n0;
  if constexpr (SYT > 0) {
    const int lin  = blockIdx.x;
    const int xcd  = lin & 7;
    const int rem  = lin >> 3;
    const int yloc = rem / SXT;
    const int x    = rem - yloc * SXT;
    m0 = (xcd * SYT + yloc) * 128;
    n0 = x * 128;
  } else {
    m0 = blockIdx.y * 128;
    n0 = blockIdx.x * 128;
  }
  const int bz = blockIdx.z;
  A += (long long)bz * sA;
  B += (long long)bz * sB;
  const float* rd = rowdiv ? rowdiv + (long long)bz * sRD : (const float*)0;

  __shared__ unsigned short As[128 * 32];
  __shared__ unsigned short Bs[128 * 32];

  floatx4 acc[4][4];
#pragma unroll
  for (int i = 0; i < 4; ++i)
#pragma unroll
    for (int j = 0; j < 4; ++j) acc[i][j] = floatx4{0.f, 0.f, 0.f, 0.f};

  const int t    = (lane & 7) ^ (lane >> 3);
  const int srow = 2 * (lane >> 3) + (t >> 2);
  const int scol = (t & 3) * 8;
  const unsigned short* ga0 = A + (long long)(m0 + wave * 32 + srow) * lda + scol;
  const unsigned short* ga1 = ga0 + 16LL * lda;
  const unsigned short* gb0 = B + (long long)(n0 + wave * 32 + srow) * ldb + scol;
  const unsigned short* gb1 = gb0 + 16LL * ldb;
  unsigned short* lA0 = As + wave * 1024;
  unsigned short* lA1 = lA0 + 512;
  unsigned short* lB0 = Bs + wave * 1024;
  unsigned short* lB1 = lB0 + 512;

  const int l15  = lane & 15;
  const int q    = lane >> 4;
  const int rofs = (l15 >> 1) * 64 + (((q + 4 * (l15 & 1)) ^ (l15 >> 1)) * 8);

  for (int kt = 0; kt < K; kt += 32) {
    __syncthreads();
    stage16(ga0 + kt, lA0);
    stage16(ga1 + kt, lA1);
    stage16(gb0 + kt, lB0);
    stage16(gb1 + kt, lB1);
    __syncthreads();
    short8 af[4], bfv[4];
#pragma unroll
    for (int i = 0; i < 4; ++i) af[i]  = *(const short8*)&As[(wr * 32 + i * 8) * 64 + rofs];
#pragma unroll
    for (int j = 0; j < 4; ++j) bfv[j] = *(const short8*)&Bs[(wc * 32 + j * 8) * 64 + rofs];
#pragma unroll
    for (int i = 0; i < 4; ++i)
#pragma unroll
      for (int j = 0; j < 4; ++j)
        acc[i][j] = __builtin_amdgcn_mfma_f32_16x16x32_bf16(bfv[j], af[i], acc[i][j], 0, 0, 0);
  }

  // Epilogue: lane holds C[row=m0+wr*64+i*16+l15][cols n0+wc*64+j*16+q*4 .. +3]
#pragma unroll
  for (int i = 0; i < 4; ++i) {
    const int row = m0 + wr * 64 + i * 16 + l15;
    const float rcp = rd ? __builtin_amdgcn_rcpf(rd[row]) : 1.0f;
#pragma unroll
    for (int j = 0; j < 4; ++j) {
      const int colb = n0 + wc * 64 + j * 16 + q * 4;
      floatx4 v = acc[i][j];
      if (rd) { v[0] *= rcp; v[1] *= rcp; v[2] *= rcp; v[3] *= rcp; }
      if (bias) {
        const float4 bi = *(const float4*)&bias[colb];
        v[0] += bi.x; v[1] += bi.y; v[2] += bi.z; v[3] += bi.w;
      }
      if (Cb) *(short4v*)&Cb[(long long)bz * sC + (long long)row * ldc + colb] = pack4(v[0], v[1], v[2], v[3]);
      else    *(floatx4*)&Cf[(long long)bz * sC + (long long)row * ldc + colb] = v;
    }
  }
}

// ---------------------------------------------------------------------------
// Fused scores + group + exp (verified r6 form; qk rows 1536 wide).
// ---------------------------------------------------------------------------
__global__ __launch_bounds__(256) void score_weights(
    const unsigned short* __restrict__ qkv, const unsigned short* __restrict__ gw,
    unsigned short* __restrict__ Wout, float* __restrict__ L,
    const float* __restrict__ alpha)
{
  const int tid  = threadIdx.x;
  const int lane = tid & 63;
  const int wave = tid >> 6;
  const int wr = wave >> 1, wc = wave & 1;
  const int n0 = blockIdx.x * 128;
  const int m0 = blockIdx.y * 128;
  const int b  = blockIdx.z;

  const int l15 = lane & 15;
  const int q   = lane >> 4;
  const int q8  = q * 8;

  const unsigned short* gq = gw + ((long long)(b * 1024 + m0 + wr * 64)) * 64;
  const unsigned short* gk = gw + ((long long)(b * 1024 + n0 + wc * 64)) * 64;
  floatx4 gacc[4][4];
#pragma unroll
  for (int i = 0; i < 4; ++i)
#pragma unroll
    for (int j = 0; j < 4; ++j) gacc[i][j] = floatx4{0.f, 0.f, 0.f, 0.f};
#pragma unroll
  for (int ks = 0; ks < 2; ++ks) {
    short8 af[4], bfv[4];
#pragma unroll
    for (int i = 0; i < 4; ++i) af[i]  = *(const short8*)&gq[(long long)(i * 16 + l15) * 64 + ks * 32 + q8];
#pragma unroll
    for (int j = 0; j < 4; ++j) bfv[j] = *(const short8*)&gk[(long long)(j * 16 + l15) * 64 + ks * 32 + q8];
#pragma unroll
    for (int i = 0; i < 4; ++i)
#pragma unroll
      for (int j = 0; j < 4; ++j)
        gacc[i][j] = __builtin_amdgcn_mfma_f32_16x16x32_bf16(bfv[j], af[i], gacc[i][j], 0, 0, 0);
  }
  const float aa    = 1.0f / (1.0f + __expf(-alpha[0]));
  const float onema = 1.0f - aa;
  half2v gfp[4][4][2];
#pragma unroll
  for (int i = 0; i < 4; ++i)
#pragma unroll
    for (int j = 0; j < 4; ++j) {
      gfp[i][j][0] = half2v{(_Float16)(aa + onema * gacc[i][j][0]),
                            (_Float16)(aa + onema * gacc[i][j][1])};
      gfp[i][j][1] = half2v{(_Float16)(aa + onema * gacc[i][j][2]),
                            (_Float16)(aa + onema * gacc[i][j][3])};
    }

  const unsigned short* Aq = qkv + ((long long)(b * 1024 + m0)) * 1536;        // q cols 0..767
  const unsigned short* Bk = qkv + ((long long)(b * 1024 + n0)) * 1536 + 768;  // k cols 768..1535

  __shared__ unsigned short As[128 * 32];
  __shared__ unsigned short Bs[128 * 32];

  floatx4 sacc[4][4];
#pragma unroll
  for (int i = 0; i < 4; ++i)
#pragma unroll
    for (int j = 0; j < 4; ++j) sacc[i][j] = floatx4{0.f, 0.f, 0.f, 0.f};

  const int t    = (lane & 7) ^ (lane >> 3);
  const int srow = 2 * (lane >> 3) + (t >> 2);
  const int scol = (t & 3) * 8;
  const unsigned short* ga0 = Aq + (long long)(wave * 32 + srow) * 1536 + scol;
  const unsigned short* ga1 = ga0 + 16LL * 1536;
  const unsigned short* gb0 = Bk + (long long)(wave * 32 + srow) * 1536 + scol;
  const unsigned short* gb1 = gb0 + 16LL * 1536;
  unsigned short* lA0 = As + wave * 1024;
  unsigned short* lA1 = lA0 + 512;
  unsigned short* lB0 = Bs + wave * 1024;
  unsigned short* lB1 = lB0 + 512;

  const int rofs = (l15 >> 1) * 64 + (((q + 4 * (l15 & 1)) ^ (l15 >> 1)) * 8);

  for (int kt = 0; kt < 768; kt += 32) {
    __syncthreads();
    stage16(ga0 + kt, lA0);
    stage16(ga1 + kt, lA1);
    stage16(gb0 + kt, lB0);
    stage16(gb1 + kt, lB1);
    __syncthreads();
    short8 af[4], bfv[4];
#pragma unroll
    for (int i = 0; i < 4; ++i) af[i]  = *(const short8*)&As[(wr * 32 + i * 8) * 64 + rofs];
#pragma unroll
    for (int j = 0; j < 4; ++j) bfv[j] = *(const short8*)&Bs[(wc * 32 + j * 8) * 64 + rofs];
#pragma unroll
    for (int i = 0; i < 4; ++i)
#pragma unroll
      for (int j = 0; j < 4; ++j)
        sacc[i][j] = __builtin_amdgcn_mfma_f32_16x16x32_bf16(bfv[j], af[i], sacc[i][j], 0, 0, 0);
  }

  const float scale = 0.03608439182435161f;
  unsigned short* Wb = Wout + ((long long)b << 20);

#pragma unroll
  for (int i = 0; i < 4; ++i) {
    const int row = m0 + wr * 64 + i * 16 + l15;
    float ls = 0.0f;
#pragma unroll
    for (int j = 0; j < 4; ++j) {
      const int colb = n0 + wc * 64 + j * 16 + q * 4;
      float e0 = __expf(sacc[i][j][0] * scale);
      float e1 = __expf(sacc[i][j][1] * scale);
      float e2 = __expf(sacc[i][j][2] * scale);
      float e3 = __expf(sacc[i][j][3] * scale);
      ls += (e0 + e1) + (e2 + e3);
      *(short4v*)&Wb[(long long)row * 1024 + colb] =
        pack4(e0 * (float)gfp[i][j][0][0], e1 * (float)gfp[i][j][0][1],
              e2 * (float)gfp[i][j][1][0], e3 * (float)gfp[i][j][1][1]);
    }
    ls += __shfl_xor(ls, 16, 64);
    ls += __shfl_xor(ls, 32, 64);
    if (lane < 16) atomicAdd(&L[b * 1024 + row], ls);
  }
}

// ---------------------------------------------------------------------------
// MFMA-based gw (verified r5/r6; qk row stride 1536).
// ---------------------------------------------------------------------------
__global__ __launch_bounds__(256) void gw_mfma(
    const unsigned short* __restrict__ qkv, const unsigned short* __restrict__ Wgp64,
    unsigned short* __restrict__ gw)
{
  const int lane = threadIdx.x & 63;
  const int wave = threadIdx.x >> 6;
  const int l15  = lane & 15;
  const int q    = lane >> 4;
  const int q8   = q * 8;
  const long long row0 = (long long)blockIdx.x * 64 + wave * 16;
  const unsigned short* A = qkv + row0 * 1536;          // q cols 0..767

  floatx4 acc[4];
#pragma unroll
  for (int j = 0; j < 4; ++j) acc[j] = floatx4{0.f, 0.f, 0.f, 0.f};

  for (int kt = 0; kt < 768; kt += 32) {
    short8 af = *(const short8*)&A[(long long)l15 * 1536 + kt + q8];
    short8 bf[4];
#pragma unroll
    for (int j = 0; j < 4; ++j)
      bf[j] = *(const short8*)&Wgp64[(j * 16 + l15) * 768 + kt + q8];
#pragma unroll
    for (int j = 0; j < 4; ++j)
      acc[j] = __builtin_amdgcn_mfma_f32_16x16x32_bf16(bf[j], af, acc[j], 0, 0, 0);
  }

  float mx = -1e30f;
#pragma unroll
  for (int j = 0; j < 4; ++j)
#pragma unroll
    for (int e = 0; e < 4; ++e) {
      const int col = j * 16 + q * 4 + e;
      if (col < 49) mx = fmaxf(mx, acc[j][e]);
    }
  mx = fmaxf(mx, __shfl_xor(mx, 16, 64));
  mx = fmaxf(mx, __shfl_xor(mx, 32, 64));

  float ev[4][4];
  float s = 0.0f;
#pragma unroll
  for (int j = 0; j < 4; ++j)
#pragma unroll
    for (int e = 0; e < 4; ++e) {
      const int col = j * 16 + q * 4 + e;
      const float x = (col < 49) ? __expf(acc[j][e] - mx) : 0.0f;
      ev[j][e] = x;
      s += x;
    }
  s += __shfl_xor(s, 16, 64);
  s += __shfl_xor(s, 32, 64);
  const float inv = 1.0f / s;

  unsigned short* out = gw + (row0 + l15) * 64;
#pragma unroll
  for (int j = 0; j < 4; ++j)
    *(short4v*)&out[j * 16 + q * 4] =
      pack4(ev[j][0] * inv, ev[j][1] * inv, ev[j][2] * inv, ev[j][3] * inv);
}

// ---------------------------------------------------------------------------
// NEW: parallel 768x768x768 bf16 GEMM for Wcomb (direct-from-global, the
// verified gw_mfma fragment convention). C[n][k] = sum_d A[n][d]*B[k][d].
// Wave: 16 A-rows x 64 B-rows; block 4 waves; grid (12,12) = 144 blocks
// (vs the 9-block 256² launch that cost ~50 us in r6).
// ---------------------------------------------------------------------------
__global__ __launch_bounds__(256) void small_gemm_nt(
    const unsigned short* __restrict__ A, const unsigned short* __restrict__ B,
    unsigned short* __restrict__ C)
{
  const int lane = threadIdx.x & 63;
  const int wave = threadIdx.x >> 6;
  const int l15  = lane & 15;
  const int q    = lane >> 4;
  const int q8   = q * 8;
  const int rows0 = (blockIdx.y * 4 + wave) * 16;
  const int cols0 = blockIdx.x * 64;

  floatx4 acc[4];
#pragma unroll
  for (int j = 0; j < 4; ++j) acc[j] = floatx4{0.f, 0.f, 0.f, 0.f};

  for (int kt = 0; kt < 768; kt += 32) {
    short8 af = *(const short8*)&A[(rows0 + l15) * 768 + kt + q8];
    short8 bf[4];
#pragma unroll
    for (int j = 0; j < 4; ++j)
      bf[j] = *(const short8*)&B[(cols0 + j * 16 + l15) * 768 + kt + q8];
#pragma unroll
    for (int j = 0; j < 4; ++j)
      acc[j] = __builtin_amdgcn_mfma_f32_16x16x32_bf16(bf[j], af, acc[j], 0, 0, 0);
  }

  unsigned short* out = C + (rows0 + l15) * 768 + cols0;
#pragma unroll
  for (int j = 0; j < 4; ++j)
    *(short4v*)&out[j * 16 + q * 4] = pack4(acc[j][0], acc[j][1], acc[j][2], acc[j][3]);
}

__global__ void convert_f2b(const float* __restrict__ in, unsigned short* __restrict__ out, long long n)
{
  long long i = ((long long)blockIdx.x * 256 + threadIdx.x) * 4;
  if (i + 3 >= n) {
    for (long long k = i; k < n; ++k) out[k] = f2b(in[k]);
    return;
  }
  float4 v = *(const float4*)(in + i);
  out[i + 0] = f2b(v.x);
  out[i + 1] = f2b(v.y);
  out[i + 2] = f2b(v.z);
  out[i + 3] = f2b(v.w);
}

__global__ void transpose_f2b(const float* __restrict__ in, unsigned short* __restrict__ out,
                              int R, int C, int ldin, int ldout)
{
  __shared__ unsigned short t[32][33];
  const int c0 = blockIdx.x * 32, r0 = blockIdx.y * 32;
  for (int i = threadIdx.y; i < 32; i += 8) {
    const int r = r0 + i, c = c0 + threadIdx.x;
    if (r < R && c < C) t[i][threadIdx.x] = f2b(in[(long long)r * ldin + c]);
  }
  __syncthreads();
  for (int i = threadIdx.y; i < 32; i += 8) {
    const int r = c0 + i, c = r0 + threadIdx.x;
    if (r < C && c < R) out[(long long)r * ldout + c] = t[threadIdx.x][i];
  }
}

// WvB[768][768] bf16 = W_qkv[:, 1536:2304] (row-major slice convert)
__global__ void slice_f2b(const float* __restrict__ in, unsigned short* __restrict__ out)
{
  const long long idx = (long long)blockIdx.x * 256 + threadIdx.x;  // < 589824
  const int r = (int)(idx / 768), c = (int)(idx - (long long)r * 768);
  out[idx] = f2b(in[(long long)r * 2304 + 1536 + c]);
}

// bias2[j] = b_proj[j] + sum_d WprojT_bf16[j][d] * b_qkv[1536+d]
// one wave per j, coalesced bf16 row reads + shuffle reduce (192 blocks).
__global__ __launch_bounds__(256) void bias2_kernel(
    const unsigned short* __restrict__ WprojT, const float* __restrict__ b_qkv,
    const float* __restrict__ b_proj, float* __restrict__ bias2)
{
  const int lane = threadIdx.x & 63;
  const int wave = threadIdx.x >> 6;
  const int j = blockIdx.x * 4 + wave;
  float s = 0.0f;
#pragma unroll
  for (int tt = 0; tt < 12; ++tt) {
    const int d = tt * 64 + lane;
    s += b2f(WprojT[j * 768 + d]) * b_qkv[1536 + d];
  }
#pragma unroll
  for (int m = 1; m < 64; m <<= 1) s += __shfl_xor(s, m, 64);
  if (lane == 0) bias2[j] = b_proj[j] + s;
}

extern "C" void kernel_launch(void* const* d_in, const int* in_sizes, int n_in,
                              void* d_out, int out_size, void* d_ws, size_t ws_size,
                              hipStream_t stream)
{
  const float* x      = (const float*)d_in[0];
  const float* W_qkv  = (const float*)d_in[1];
  const float* b_qkv  = (const float*)d_in[2];
  const float* W_proj = (const float*)d_in[3];
  const float* b_proj = (const float*)d_in[4];
  const float* W_gp   = (const float*)d_in[5];
  const float* alpha  = (const float*)d_in[6];

  char* p = (char*)d_ws;
  auto alloc = [&](size_t bytes) { char* r = p; p += (bytes + 255) & ~255ULL; return r; };
  unsigned short* qk     = (unsigned short*)alloc(16384ULL * 1536 * 2);   // q|k rows
  unsigned short* xb     = (unsigned short*)alloc(16384ULL * 768 * 2);
  unsigned short* WqkvT  = (unsigned short*)alloc(1536ULL * 768 * 2);     // q,k cols only
  unsigned short* WprojT = (unsigned short*)alloc(768ULL * 768 * 2);
  unsigned short* WvB    = (unsigned short*)alloc(768ULL * 768 * 2);      // Wv row-major bf16
  unsigned short* Wcomb  = (unsigned short*)alloc(768ULL * 768 * 2);      // (Wv @ W_proj)^T entries
  unsigned short* Wgp64  = (unsigned short*)alloc(64ULL * 768 * 2);       // zero-padded rows 49..63
  unsigned short* gwbuf  = (unsigned short*)alloc(16384ULL * 64 * 2);
  float*          Lbuf   = (float*)alloc(16384ULL * 4);
  float*          bias2  = (float*)alloc(768ULL * 4);
  unsigned short* wmat   = (unsigned short*)alloc(16ULL * 1024 * 1024 * 2);
  unsigned short* vpT    = (unsigned short*)alloc(16ULL * 768 * 1024 * 2);

  const dim3 blk256(256);
  const dim3 tb(32, 8);

  // input conversions / transposes (fp32 -> bf16)
  convert_f2b<<<dim3(12288), blk256, 0, stream>>>(x, xb, 16384LL * 768);
  transpose_f2b<<<dim3(48, 24), tb, 0, stream>>>(W_qkv, WqkvT, 768, 1536, 2304, 768);
  transpose_f2b<<<dim3(24, 24), tb, 0, stream>>>(W_proj, WprojT, 768, 768, 768, 768);
  hipMemsetAsync(Wgp64, 0, 64ULL * 768 * 2, stream);
  transpose_f2b<<<dim3(2, 24), tb, 0, stream>>>(W_gp, Wgp64, 768, 49, 49, 768);
  slice_f2b<<<dim3(2304), blk256, 0, stream>>>(W_qkv, WvB);

  // Wcomb[n][k] = sum_d WprojT[n][d] * WvB[k][d]   (144-block MFMA kernel)
  small_gemm_nt<<<dim3(12, 12), blk256, 0, stream>>>(WprojT, WvB, Wcomb);
  // bias2 = b_proj + W_proj^T @ b_qkv[1536:2304]   (192 blocks, wave/output)
  bias2_kernel<<<dim3(192), blk256, 0, stream>>>(WprojT, b_qkv, b_proj, bias2);

  // qk = x @ W_qkv[:, :1536] + b_qkv[:1536]
  // 1536 blocks = 8 xcd * 16 ytiles * 12 xtiles (bijective swizzle)
  gemm_bt<16, 12><<<dim3(1536, 1, 1), blk256, 0, stream>>>(xb, WqkvT, qk, (float*)0,
                                                           (const float*)0, b_qkv,
                                                           768, 768, 768, 1536, 0, 0, 0, 0);

  // gw = softmax(q @ W_gp), padded to 64
  gw_mfma<<<dim3(256), blk256, 0, stream>>>(qk, Wgp64, gwbuf);

  hipMemsetAsync(Lbuf, 0, 16384 * 4, stream);

  // weights (unnormalized) + L
  score_weights<<<dim3(8, 8, 16), blk256, 0, stream>>>(qk, gwbuf, wmat, Lbuf, alpha);

  // vpT[b][n][m] = sum_k Wcomb[n][k] * x[b][m][k]   (v never materialized)
  gemm_bt<0, 0><<<dim3(8, 6, 16), blk256, 0, stream>>>(Wcomb, xb, vpT, (float*)0,
                                                       (const float*)0, (const float*)0,
                                                       768, 768, 768, 1024,
                                                       0, 1024LL * 768, 768LL * 1024, 0);

  // out[m][j] = (1/L[m]) * sum_n wmat[m][n] * vpT[j][n] + bias2[j]   (fp32 out)
  gemm_bt<0, 0><<<dim3(6, 8, 16), blk256, 0, stream>>>(wmat, vpT, (unsigned short*)0, (float*)d_out,
                                                       Lbuf, bias2,
                                                       1024, 1024, 1024, 768,
                                                       1024LL * 1024, 768LL * 1024, 1024LL * 768, 1024);
}